// Round 8
// baseline (265.662 us; speedup 1.0000x reference)
//
#include <hip/hip_runtime.h>
#include <hip/hip_bf16.h>

#define N_NODES 50000
#define N_EDGES 800000
#define N_GRAPH 128
#define NC      10

// bucket sort params
#define NBKT  391        // ceil(50000/128) buckets of 128 node ids
#define BLK_E 4096       // edges per pass-A block
#define NPT   16         // edges per thread in pass A (BLK_E/256)
#define BCAP  2560       // capacity per bucket region (avg 2046, 11 sigma slack)

typedef __attribute__((ext_vector_type(8))) short bf16x8;
typedef __attribute__((ext_vector_type(4))) float f32x4;

static constexpr size_t alignup(size_t x) { return (x + 511) & ~size_t(511); }

// ---------------- workspace layout (bytes) ----------------
static constexpr size_t OFS_IMB   = 0;                                           // [N,128] bf16 (im + b_conv)
static constexpr size_t OFS_CURB  = alignup(OFS_IMB + (size_t)N_NODES*128*2);    // [N,128] bf16 cur
static constexpr size_t OFS_ZB    = alignup(OFS_CURB + (size_t)N_NODES*128*2);   // [N,128] bf16 z / out
static constexpr size_t OFS_OFF   = alignup(OFS_ZB + (size_t)N_NODES*128*2);     // [N+1] int
static constexpr size_t OFS_GCUR  = alignup(OFS_OFF + (size_t)(N_NODES+1)*4);    // [512] int bucket cursors
static constexpr size_t OFS_CSB   = alignup(OFS_GCUR + 2048);                    // [512] int bucket csr base
static constexpr size_t OFS_CSR   = alignup(OFS_CSB + 2048);                     // [E] int
static constexpr size_t OFS_BKT   = alignup(OFS_CSR + (size_t)N_EDGES*4);        // [NBKT*BCAP] u32
static constexpr size_t OFS_EMB   = alignup(OFS_BKT + (size_t)NBKT*BCAP*4);      // [128,128] f32
static constexpr size_t OFS_NLL   = alignup(OFS_EMB + 128*128*4);                // [128] f32
static constexpr size_t OFS_COR   = alignup(OFS_NLL + 128*4);                    // [128] f32
static constexpr size_t OFS_WPK   = alignup(OFS_COR + 128*4);                    // 3 mats x 2 halves x 16384 ushort

__device__ __forceinline__ unsigned short f2bf(float f)
{
    unsigned u = __float_as_uint(f);
    u += 0x7fffu + ((u >> 16) & 1u);          // RNE
    return (unsigned short)(u >> 16);
}

// =====================================================================
// Setup: pack 3 weight matrices into MFMA fragment order (bf16 hi+lo)
// AND zero gcur/embed — one launch, no rocclr fill blits in the graph.
// Blocks 0..191: pack (64 blocks per matrix). Blocks 192..255: zeroing.
// frag index: f = ((ct*4 + ks)*64 + lane)*8 + j
//   c = ct*16 + (lane&15), k = ks*32 + (lane>>4)*8 + j
// =====================================================================
__global__ __launch_bounds__(256) void setup_kernel(
    const float* __restrict__ W0, const float* __restrict__ W1, const float* __restrict__ W2,
    unsigned short* __restrict__ wpk,   // [6][16384]: w0h w0l w1h w1l w2h w2l
    int* __restrict__ gcur, float* __restrict__ embed)
{
    int b = blockIdx.x;
    if (b < 192) {
        int mat = b >> 6;
        const float* W = (mat == 0) ? W0 : (mat == 1) ? W1 : W2;
        unsigned short* Wh = wpk + (size_t)(2 * mat) * 16384;
        unsigned short* Wl = Wh + 16384;
        int f = (b & 63) * 256 + threadIdx.x;
        int j    = f & 7;
        int lane = (f >> 3) & 63;
        int ctks = f >> 9;
        int ct = ctks >> 2, ks = ctks & 3;
        int c = ct * 16 + (lane & 15);
        int k = ks * 32 + (lane >> 4) * 8 + j;
        float v = W[c * 128 + k];
        unsigned short h = f2bf(v);
        float hf = __uint_as_float((unsigned)h << 16);
        Wh[f] = h;
        Wl[f] = f2bf(v - hf);
    } else {
        int i = (b - 192) * 256 + threadIdx.x;   // 0..16383
        embed[i] = 0.f;
        if (i < 512) gcur[i] = 0;
    }
}

// =====================================================================
// First GEMM (f32 A, hi/lo split): im = A @ W0.T + b_n2l
//   curb = bf16(relu(im)) ; imb = bf16(im + b_conv)   [b_conv folded]
// NT=2 node-tiles per wave: W fragments reused 2x.
// =====================================================================
__global__ __launch_bounds__(256) void gemm_n2l(
    const float* __restrict__ A,
    const unsigned short* __restrict__ Wh, const unsigned short* __restrict__ Wl,
    const float* __restrict__ b_n2l, const float* __restrict__ b_conv,
    unsigned short* __restrict__ curb, unsigned short* __restrict__ imb, int M)
{
    const int NT = 2;
    int wid  = threadIdx.x >> 6;
    int lane = threadIdx.x & 63;
    int kb = lane >> 4, m = lane & 15;
    int base = blockIdx.x * (64 * NT) + wid * (16 * NT);
    if (base >= M) return;

    f32x4 acc[NT][8];
#pragma unroll
    for (int i = 0; i < NT; ++i)
#pragma unroll
        for (int ct = 0; ct < 8; ++ct) acc[i][ct] = (f32x4){0.f, 0.f, 0.f, 0.f};

    int rows[NT]; bool act[NT];
#pragma unroll
    for (int i = 0; i < NT; ++i) {
        act[i] = (base + 16 * i) < M;        // M % 16 == 0: tiles all-or-nothing
        rows[i] = act[i] ? (base + 16 * i + m) : 0;
    }

#pragma unroll
    for (int ks = 0; ks < 4; ++ks) {
        bf16x8 ah[NT], al[NT];
#pragma unroll
        for (int i = 0; i < NT; ++i) {
            f32x4 a0 = *(const f32x4*)(A + (size_t)rows[i] * 128 + ks * 32 + kb * 8);
            f32x4 a1 = *(const f32x4*)(A + (size_t)rows[i] * 128 + ks * 32 + kb * 8 + 4);
            float av[8] = {a0[0], a0[1], a0[2], a0[3], a1[0], a1[1], a1[2], a1[3]};
#pragma unroll
            for (int j = 0; j < 8; ++j) {
                unsigned short h = f2bf(av[j]);
                float hf = __uint_as_float((unsigned)h << 16);
                ah[i][j] = (short)h;
                al[i][j] = (short)f2bf(av[j] - hf);
            }
        }
#pragma unroll
        for (int ct = 0; ct < 8; ++ct) {
            size_t wf = ((size_t)(ct * 4 + ks) * 64 + lane) * 8;
            bf16x8 wh = *(const bf16x8*)(Wh + wf);
            bf16x8 wl = *(const bf16x8*)(Wl + wf);
#pragma unroll
            for (int i = 0; i < NT; ++i) {
                acc[i][ct] = __builtin_amdgcn_mfma_f32_16x16x32_bf16(wh, ah[i], acc[i][ct], 0, 0, 0);
                acc[i][ct] = __builtin_amdgcn_mfma_f32_16x16x32_bf16(wh, al[i], acc[i][ct], 0, 0, 0);
                acc[i][ct] = __builtin_amdgcn_mfma_f32_16x16x32_bf16(wl, ah[i], acc[i][ct], 0, 0, 0);
            }
        }
    }

#pragma unroll
    for (int i = 0; i < NT; ++i) {
        if (!act[i]) continue;
        int row = rows[i];
#pragma unroll
        for (int ct = 0; ct < 8; ++ct) {
            int c0 = ct * 16 + kb * 4;
            f32x4 r = acc[i][ct];
            f32x4 bv = *(const f32x4*)(b_n2l + c0);
            f32x4 cv = *(const f32x4*)(b_conv + c0);
            r += bv;
            // imb = bf16(im + b_conv)
            ushort4 oi;
            oi.x = f2bf(r[0] + cv[0]); oi.y = f2bf(r[1] + cv[1]);
            oi.z = f2bf(r[2] + cv[2]); oi.w = f2bf(r[3] + cv[3]);
            *(ushort4*)(imb + (size_t)row * 128 + c0) = oi;
            // curb = bf16(relu(im))
            ushort4 oc;
            oc.x = f2bf(fmaxf(r[0], 0.f)); oc.y = f2bf(fmaxf(r[1], 0.f));
            oc.z = f2bf(fmaxf(r[2], 0.f)); oc.w = f2bf(fmaxf(r[3], 0.f));
            *(ushort4*)(curb + (size_t)row * 128 + c0) = oc;
        }
    }
}

// =====================================================================
// bf16 GEMM (C^T tiles, no LDS): out = A @ W.T (+bias) (+relu), bf16 out.
// NT=4 node-tiles per wave: W fragments reused 4x (W traffic /4).
// =====================================================================
template <bool RELU>
__global__ __launch_bounds__(256) void gemm_bf16(
    const unsigned short* __restrict__ A,
    const unsigned short* __restrict__ Wh, const unsigned short* __restrict__ Wl,
    const float* __restrict__ bias,
    unsigned short* __restrict__ out_bf16, int M)
{
    const int NT = 4;
    int wid  = threadIdx.x >> 6;
    int lane = threadIdx.x & 63;
    int kb = lane >> 4, m = lane & 15;
    int base = blockIdx.x * (64 * NT) + wid * (16 * NT);
    if (base >= M) return;

    f32x4 acc[NT][8];
#pragma unroll
    for (int i = 0; i < NT; ++i)
#pragma unroll
        for (int ct = 0; ct < 8; ++ct) acc[i][ct] = (f32x4){0.f, 0.f, 0.f, 0.f};

    int rows[NT]; bool act[NT];
#pragma unroll
    for (int i = 0; i < NT; ++i) {
        act[i] = (base + 16 * i) < M;
        rows[i] = act[i] ? (base + 16 * i + m) : 0;
    }

#pragma unroll
    for (int ks = 0; ks < 4; ++ks) {
        bf16x8 ah[NT], al[NT];
#pragma unroll
        for (int i = 0; i < NT; ++i) {
            const unsigned short* p = A + (size_t)rows[i] * 128 + ks * 32 + kb * 8;
            ah[i] = *(const bf16x8*)p;
        }
#pragma unroll
        for (int ct = 0; ct < 8; ++ct) {
            size_t wf = ((size_t)(ct * 4 + ks) * 64 + lane) * 8;
            bf16x8 wh = *(const bf16x8*)(Wh + wf);
            bf16x8 wl = *(const bf16x8*)(Wl + wf);
#pragma unroll
            for (int i = 0; i < NT; ++i) {
                acc[i][ct] = __builtin_amdgcn_mfma_f32_16x16x32_bf16(wh, ah[i], acc[i][ct], 0, 0, 0);
                acc[i][ct] = __builtin_amdgcn_mfma_f32_16x16x32_bf16(wl, ah[i], acc[i][ct], 0, 0, 0);
            }
        }
    }

#pragma unroll
    for (int i = 0; i < NT; ++i) {
        if (!act[i]) continue;
        int row = rows[i];
#pragma unroll
        for (int ct = 0; ct < 8; ++ct) {
            int c0 = ct * 16 + kb * 4;
            f32x4 r = acc[i][ct];
            if (bias) {
                f32x4 bv = *(const f32x4*)(bias + c0);
                r += bv;
            }
            if (RELU) {
                r[0] = fmaxf(r[0], 0.f); r[1] = fmaxf(r[1], 0.f);
                r[2] = fmaxf(r[2], 0.f); r[3] = fmaxf(r[3], 0.f);
            }
            ushort4 ob;
            ob.x = f2bf(r[0]); ob.y = f2bf(r[1]); ob.z = f2bf(r[2]); ob.w = f2bf(r[3]);
            *(ushort4*)(out_bf16 + (size_t)row * 128 + c0) = ob;
        }
    }
}

// =====================================================================
// Pass A: LDS counting-sort 4096 edges into 391 coarse buckets (dst>>7),
// write each bucket run contiguously to its global region (atomic reserve).
// Edge packed as (src<<7)|(dst&127) — 4B.
// =====================================================================
__global__ __launch_bounds__(256) void bucket_a(
    const int* __restrict__ esrc, const int* __restrict__ edst,
    int* __restrict__ gcur, unsigned* __restrict__ bdata)
{
    __shared__ unsigned sp[BLK_E];      // 16KB
    __shared__ int shist[512];
    __shared__ int sscan[512];
    __shared__ int sgbase[NBKT];
    __shared__ int scur[NBKT];
    __shared__ int wtot[4];

    int t = threadIdx.x;
    int e0 = blockIdx.x * BLK_E;
    shist[t] = 0; shist[t + 256] = 0;
    __syncthreads();

    int vv[NPT]; int bb[NPT];
#pragma unroll
    for (int i = 0; i < NPT; ++i) {
        int e = e0 + t + i * 256;
        if (e < N_EDGES) {
            int s = esrc[e], d = edst[e];
            bb[i] = d >> 7;
            vv[i] = (s << 7) | (d & 127);
            atomicAdd(&shist[bb[i]], 1);
        } else bb[i] = -1;
    }
    __syncthreads();

    // exclusive scan of 512 counts
    {
        int lane = t & 63, w = t >> 6;
        int a0 = shist[2 * t], a1 = shist[2 * t + 1];
        int s = a0 + a1, inc = s;
#pragma unroll
        for (int d = 1; d < 64; d <<= 1) {
            int y = __shfl_up(inc, d, 64);
            if (lane >= d) inc += y;
        }
        if (lane == 63) wtot[w] = inc;
        __syncthreads();
        int woff = 0;
        for (int j = 0; j < w; ++j) woff += wtot[j];
        int excl = woff + inc - s;
        sscan[2 * t] = excl;
        sscan[2 * t + 1] = excl + a0;
    }
    __syncthreads();

    // reserve global space per bucket; init local cursors
    for (int b = t; b < NBKT; b += 256) {
        int c = shist[b];
        sgbase[b] = c ? atomicAdd(&gcur[b], c) : 0;
        scur[b] = sscan[b];
    }
    __syncthreads();

    // scatter into LDS grouped by bucket
#pragma unroll
    for (int i = 0; i < NPT; ++i) {
        if (bb[i] >= 0) {
            int pos = atomicAdd(&scur[bb[i]], 1);
            sp[pos] = (unsigned)vv[i];
        }
    }
    __syncthreads();

    // copy runs out: wave w handles buckets w, w+4, ...
    int lane = t & 63, w = t >> 6;
    for (int b = w; b < NBKT; b += 4) {
        int c = shist[b];
        int lo = sscan[b];
        unsigned gb = (unsigned)b * BCAP + (unsigned)sgbase[b];
        for (int j = lane; j < c; j += 64)
            bdata[gb + j] = sp[lo + j];
    }
}

// =====================================================================
// Exclusive scan of 391 bucket counts -> csr base per bucket; off[N]=E.
// =====================================================================
__global__ __launch_bounds__(256) void scan_buckets(
    const int* __restrict__ gcur, int* __restrict__ csrbase, int* __restrict__ off)
{
    __shared__ int wtot[4];
    int t = threadIdx.x;
    int lane = t & 63, w = t >> 6;
    int a0 = (2 * t < NBKT) ? gcur[2 * t] : 0;
    int a1 = (2 * t + 1 < NBKT) ? gcur[2 * t + 1] : 0;
    int s = a0 + a1, inc = s;
#pragma unroll
    for (int d = 1; d < 64; d <<= 1) {
        int y = __shfl_up(inc, d, 64);
        if (lane >= d) inc += y;
    }
    if (lane == 63) wtot[w] = inc;
    __syncthreads();
    int woff = 0;
    for (int j = 0; j < w; ++j) woff += wtot[j];
    int excl = woff + inc - s;
    if (2 * t < NBKT) csrbase[2 * t] = excl;
    if (2 * t + 1 < NBKT) csrbase[2 * t + 1] = excl + a0;
    if (t == 0) off[N_NODES] = N_EDGES;
}

// =====================================================================
// Pass B: per bucket, LDS counting-sort by dst&127; write off[] and csr
// fully sequentially.
// =====================================================================
__global__ __launch_bounds__(256) void bucket_b(
    const int* __restrict__ gcur, const int* __restrict__ csrbase,
    const unsigned* __restrict__ bdata,
    int* __restrict__ off, int* __restrict__ csr)
{
    __shared__ unsigned sp[BCAP];       // 10KB
    __shared__ unsigned sq[BCAP];       // 10KB
    __shared__ int h[128], sc[128], cur[128];

    int b = blockIdx.x;
    int t = threadIdx.x;
    int cnt = gcur[b];
    if (cnt > BCAP) cnt = BCAP;         // defensive (statistically impossible)
    const unsigned* reg = bdata + (size_t)b * BCAP;

    if (t < 128) h[t] = 0;
    __syncthreads();
    for (int i = t; i < cnt; i += 256) {
        unsigned v = reg[i];
        sp[i] = v;
        atomicAdd(&h[v & 127], 1);
    }
    __syncthreads();
    if (t < 64) {
        int a0 = h[2 * t], a1 = h[2 * t + 1];
        int s = a0 + a1, inc = s;
#pragma unroll
        for (int d = 1; d < 64; d <<= 1) {
            int y = __shfl_up(inc, d, 64);
            if (t >= d) inc += y;
        }
        int excl = inc - s;
        sc[2 * t] = excl;          cur[2 * t] = excl;
        sc[2 * t + 1] = excl + a0; cur[2 * t + 1] = excl + a0;
    }
    __syncthreads();
    int base = csrbase[b];
    if (t < 128) {
        int node = b * 128 + t;
        if (node < N_NODES) off[node] = base + sc[t];
    }
    for (int i = t; i < cnt; i += 256) {
        unsigned v = sp[i];
        int pos = atomicAdd(&cur[v & 127], 1);
        sq[pos] = v >> 7;
    }
    __syncthreads();
    for (int i = t; i < cnt; i += 256)
        csr[base + i] = (int)sq[i];
}

// =====================================================================
// SpMM + level epilogue: cur[n] = relu( sum_{e in row n} Z[csr[e]] + imb[n] )
// one wave per node; lane handles 2 channels (4B). unroll 8 for MLP.
// =====================================================================
__global__ __launch_bounds__(64) void spmm_ep(
    const int* __restrict__ off, const int* __restrict__ csr,
    const unsigned short* __restrict__ Z,
    const unsigned short* __restrict__ imb,
    unsigned short* __restrict__ curOut)
{
    int n = blockIdx.x;
    int t = threadIdx.x;
    int lo = off[n], hi = off[n + 1];
    float ax = 0.f, ay = 0.f;
    int e = lo;
    for (; e + 8 <= hi; e += 8) {
        unsigned v[8];
#pragma unroll
        for (int j = 0; j < 8; ++j) {
            int s = csr[e + j];
            v[j] = *(const unsigned*)(Z + (size_t)s * 128 + 2 * t);
        }
#pragma unroll
        for (int j = 0; j < 8; ++j) {
            ax += __uint_as_float(v[j] << 16);
            ay += __uint_as_float(v[j] & 0xffff0000u);
        }
    }
    for (; e + 4 <= hi; e += 4) {
        unsigned v0 = *(const unsigned*)(Z + (size_t)csr[e] * 128 + 2 * t);
        unsigned v1 = *(const unsigned*)(Z + (size_t)csr[e + 1] * 128 + 2 * t);
        unsigned v2 = *(const unsigned*)(Z + (size_t)csr[e + 2] * 128 + 2 * t);
        unsigned v3 = *(const unsigned*)(Z + (size_t)csr[e + 3] * 128 + 2 * t);
        ax += __uint_as_float(v0 << 16) + __uint_as_float(v1 << 16)
            + __uint_as_float(v2 << 16) + __uint_as_float(v3 << 16);
        ay += __uint_as_float(v0 & 0xffff0000u) + __uint_as_float(v1 & 0xffff0000u)
            + __uint_as_float(v2 & 0xffff0000u) + __uint_as_float(v3 & 0xffff0000u);
    }
    for (; e < hi; ++e) {
        unsigned v = *(const unsigned*)(Z + (size_t)csr[e] * 128 + 2 * t);
        ax += __uint_as_float(v << 16);
        ay += __uint_as_float(v & 0xffff0000u);
    }
    unsigned ib = *(const unsigned*)(imb + (size_t)n * 128 + 2 * t);
    float rx = fmaxf(ax + __uint_as_float(ib << 16), 0.f);
    float ry = fmaxf(ay + __uint_as_float(ib & 0xffff0000u), 0.f);
    unsigned outv = (unsigned)f2bf(rx) | ((unsigned)f2bf(ry) << 16);
    *(unsigned*)(curOut + (size_t)n * 128 + 2 * t) = outv;
}

// =====================================================================
// Per-graph sum pooling (bf16 input): chunked partial sums + atomicAdd.
// =====================================================================
#define PCHUNK 64
__global__ __launch_bounds__(128) void pool_partial(
    const unsigned short* __restrict__ X, const int* __restrict__ gid,
    float* __restrict__ embed)
{
    int n0 = blockIdx.x * PCHUNK;
    int t = threadIdx.x;
    int end = n0 + PCHUNK; if (end > N_NODES) end = N_NODES;
    float acc = 0.f;
    int g = gid[n0];
    for (int n = n0; n < end; ++n) {
        int gn = gid[n];
        if (gn != g) {
            atomicAdd(&embed[g * 128 + t], acc);
            acc = 0.f; g = gn;
        }
        acc += __uint_as_float((unsigned)X[(size_t)n * 128 + t] << 16);
    }
    atomicAdd(&embed[g * 128 + t], acc);
}

// =====================================================================
// Classifier head (f32).
// =====================================================================
__global__ __launch_bounds__(256) void head_kernel(
    const float* __restrict__ embed,
    const float* __restrict__ w_h1, const float* __restrict__ b_h1,
    const float* __restrict__ w_h2, const float* __restrict__ b_h2,
    const int* __restrict__ labels,
    float* __restrict__ logits, float* __restrict__ nll, float* __restrict__ corr)
{
    int g = blockIdx.x;
    int t = threadIdx.x;
    __shared__ float se[128];
    __shared__ float sh[256];
    __shared__ float sl[NC];
    __shared__ float s_lse;
    if (t < 128) se[t] = fmaxf(embed[g * 128 + t], 0.f);
    __syncthreads();

    float h = b_h1[t];
    const float* wr = w_h1 + (size_t)t * 128;
    for (int k = 0; k < 128; ++k) h += se[k] * wr[k];
    sh[t] = fmaxf(h, 0.f);
    __syncthreads();

    if (t < NC) {
        float z = b_h2[t];
        const float* w2 = w_h2 + (size_t)t * 256;
        for (int k = 0; k < 256; ++k) z += sh[k] * w2[k];
        sl[t] = z;
    }
    __syncthreads();

    if (t == 0) {
        float m = sl[0];
        int am = 0;
        for (int c = 1; c < NC; ++c) if (sl[c] > m) { m = sl[c]; am = c; }
        float s = 0.f;
        for (int c = 0; c < NC; ++c) s += expf(sl[c] - m);
        float lse = m + logf(s);
        s_lse = lse;
        int lab = labels[g];
        nll[g] = lse - sl[lab];
        corr[g] = (am == lab) ? 1.f : 0.f;
    }
    __syncthreads();
    if (t < NC) logits[g * NC + t] = sl[t] - s_lse;
}

__global__ __launch_bounds__(64) void finalize_kernel(
    const float* __restrict__ nll, const float* __restrict__ corr,
    float* __restrict__ out)
{
    int t = threadIdx.x;
    float a = nll[t] + nll[t + 64];
    float b = corr[t] + corr[t + 64];
    for (int d = 32; d; d >>= 1) {
        a += __shfl_down(a, d);
        b += __shfl_down(b, d);
    }
    if (t == 0) {
        out[N_GRAPH * NC + 0] = a / (float)N_GRAPH;
        out[N_GRAPH * NC + 1] = b / (float)N_GRAPH;
    }
}

// =====================================================================
extern "C" void kernel_launch(void* const* d_in, const int* in_sizes, int n_in,
                              void* d_out, int out_size, void* d_ws, size_t ws_size,
                              hipStream_t stream)
{
    const float* node_feat = (const float*)d_in[0];
    const int*   edge_src  = (const int*)d_in[1];
    const int*   edge_dst  = (const int*)d_in[2];
    const int*   graph_id  = (const int*)d_in[3];
    const int*   labels    = (const int*)d_in[4];
    const float* w_n2l     = (const float*)d_in[5];
    const float* b_n2l     = (const float*)d_in[6];
    const float* w_conv    = (const float*)d_in[7];
    const float* b_conv    = (const float*)d_in[8];
    const float* w_out     = (const float*)d_in[9];
    const float* b_out     = (const float*)d_in[10];
    const float* w_h1      = (const float*)d_in[11];
    const float* b_h1      = (const float*)d_in[12];
    const float* w_h2      = (const float*)d_in[13];
    const float* b_h2      = (const float*)d_in[14];

    char* ws = (char*)d_ws;
    unsigned short* imb     = (unsigned short*)(ws + OFS_IMB);
    unsigned short* curb    = (unsigned short*)(ws + OFS_CURB);
    unsigned short* zb      = (unsigned short*)(ws + OFS_ZB);
    int*            off     = (int*)(ws + OFS_OFF);
    int*            gcur    = (int*)(ws + OFS_GCUR);
    int*            csrbase = (int*)(ws + OFS_CSB);
    int*            csr     = (int*)(ws + OFS_CSR);
    unsigned*       bdata   = (unsigned*)(ws + OFS_BKT);
    float*          embed   = (float*)(ws + OFS_EMB);
    float*          nll     = (float*)(ws + OFS_NLL);
    float*          corr    = (float*)(ws + OFS_COR);
    unsigned short* wpk     = (unsigned short*)(ws + OFS_WPK);
    unsigned short* w0h = wpk;              unsigned short* w0l = wpk + 16384;
    unsigned short* w1h = wpk + 2 * 16384;  unsigned short* w1l = wpk + 3 * 16384;
    unsigned short* w2h = wpk + 4 * 16384;  unsigned short* w2l = wpk + 5 * 16384;
    float*          outp    = (float*)d_out;

    const int n2l_blocks = (N_NODES + 127) / 128;    // NT=2: 128 nodes/block
    const int gz_blocks  = (N_NODES + 255) / 256;    // NT=4: 256 nodes/block
    const int pool_blocks = (N_NODES + PCHUNK - 1) / PCHUNK;
    const int bktA_blocks = (N_EDGES + BLK_E - 1) / BLK_E;

    // 0. pack weights (MFMA fragment order, hi/lo) + zero gcur/embed
    setup_kernel<<<256, 256, 0, stream>>>(w_n2l, w_conv, w_out, wpk, gcur, embed);

    // 1. im GEMM: curb = bf16(relu(im)); imb = bf16(im + b_conv)
    gemm_n2l<<<n2l_blocks, 256, 0, stream>>>(
        node_feat, w0h, w0l, b_n2l, b_conv, curb, imb, N_NODES);

    // 2. build CSR by dst (two-pass bucket sort, cache-friendly writes)
    bucket_a<<<bktA_blocks, 256, 0, stream>>>(edge_src, edge_dst, gcur, bdata);
    scan_buckets<<<1, 256, 0, stream>>>(gcur, csrbase, off);
    bucket_b<<<NBKT, 256, 0, stream>>>(gcur, csrbase, bdata, off, csr);

    // 3. three mean-field levels via linearity: z = cur @ Wc.T (GEMM first),
    //    then cur = relu(spmm(z) + imb) with fused epilogue.
    for (int lv = 0; lv < 3; ++lv) {
        gemm_bf16<false><<<gz_blocks, 256, 0, stream>>>(
            curb, w1h, w1l, nullptr, zb, N_NODES);
        spmm_ep<<<N_NODES, 64, 0, stream>>>(off, csr, zb, imb, curb);
    }

    // 4. out = relu(curb @ w_out.T + b_out) -> bf16 into zb
    gemm_bf16<true><<<gz_blocks, 256, 0, stream>>>(
        curb, w2h, w2l, b_out, zb, N_NODES);

    // 5. per-graph pooling (sum, relu deferred to head)
    pool_partial<<<pool_blocks, 128, 0, stream>>>(zb, graph_id, embed);

    // 6. classifier head
    head_kernel<<<N_GRAPH, 256, 0, stream>>>(embed, w_h1, b_h1, w_h2, b_h2, labels,
                                             outp, nll, corr);

    // 7. loss & acc
    finalize_kernel<<<1, 64, 0, stream>>>(nll, corr, outp);
}